// Round 10
// baseline (56.758 us; speedup 1.0000x reference)
//
#include <hip/hip_runtime.h>
#include <math.h>

// Problem constants (from reference)
#define M_SLOTS 64
#define E_DIM   64
#define KEY_DIM 64
#define V_DIM   128
#define K_CAT   4
#define S_LEN   200

typedef __attribute__((ext_vector_type(8))) short short8;
typedef __attribute__((ext_vector_type(4))) float f32x4;

// ---------------- ws layout (float offsets) ----------------
#define OFF_CT     0                          // 4096 ushort = 2048 f  (Ct[m][e] bf16)
#define OFF_BM     2048                       // 64
#define OFF_WBAR   2112                       // 64
#define OFF_BBAR   2176                       // 1
#define OFF_RM0    2240                       // 64
#define OFF_P0     2304                       // 64
#define OFF_WSUM   2368                       // S*M = 12800 (zeroed by k_pre)
#define OFF_EMSUM  (OFF_WSUM + S_LEN*M_SLOTS) // 200 (zeroed, contiguous w/ wsum)

// work-item ranges for k_pre
#define PRE_CT_END   4096
#define PRE_BM_END   4160
#define PRE_WBAR_END 4224
#define PRE_BBAR     4224
#define PRE_RM_BEG   4225
#define PRE_RM_END   4289
#define PRE_Z_BEG    4289
#define PRE_Z_END    (4289 + S_LEN*M_SLOTS + S_LEN)

// pack two f32 -> bf16 pair, round-to-nearest-even (for MFMA inputs)
__device__ __forceinline__ unsigned pk2rne(float lo, float hi) {
    unsigned ul = __float_as_uint(lo); ul += 0x7fffu + ((ul >> 16) & 1u);
    unsigned uh = __float_as_uint(hi); uh += 0x7fffu + ((uh >> 16) & 1u);
    return __builtin_amdgcn_perm(uh, ul, 0x07060302u);
}
__device__ __forceinline__ unsigned short bf16rne(float f) {
    unsigned u = __float_as_uint(f);
    return (unsigned short)((u + 0x7fffu + ((u >> 16) & 1u)) >> 16);
}
__device__ __forceinline__ short8 as_s8(uint4 u) { return __builtin_bit_cast(short8, u); }

__device__ __forceinline__ void gpcm_store(float th, int q,
                                           const float* __restrict__ alpha_mean,
                                           const float* __restrict__ beta_base,
                                           const float* __restrict__ beta_gaps,
                                           float* __restrict__ out, size_t idx) {
    float a  = __expf(alpha_mean[q]);
    float b0 = beta_base[q];
    float2 g = *reinterpret_cast<const float2*>(&beta_gaps[q * (K_CAT - 2)]);
    float g0 = log1pf(__expf(g.x));
    float g1 = log1pf(__expf(g.y));
    float be1 = b0 + g0;
    float be2 = be1 + g1;
    float z0 = a * (th - b0);
    float z1 = a * (th - be1);
    float z2 = a * (th - be2);
    float c1 = z0, c2 = z0 + z1, c3 = z0 + z1 + z2;
    float cm = fmaxf(fmaxf(0.f, c1), fmaxf(c2, c3));
    float e0 = __expf(0.f - cm), e1 = __expf(c1 - cm), e2 = __expf(c2 - cm), e3 = __expf(c3 - cm);
    float si = __fdividef(1.0f, e0 + e1 + e2 + e3);
    float4 o4 = make_float4(e0 * si, e1 * si, e2 * si, e3 * si);
    *reinterpret_cast<float4*>(&out[idx * K_CAT]) = o4;
}

// 16x16x32 MFMA logits: wave covers 16 pairs. Lane: p16 = lane&15 (pair/col),
// kg = lane>>4 (k-slice + acc row group). acc[mt][reg] = logit for
// m = mt*16 + kg*4 + reg, pair p16. A = Ct[m][e] (bf16, row-major), B = q-row.
__device__ __forceinline__ void mfma_logits16(
    const float* __restrict__ qrow, const unsigned short* __restrict__ ct,
    const float* __restrict__ bm, int kg, int p16, f32x4 acc[4])
{
    // q-row slices: chunk c covers e = c*32 + kg*8 .. +7
    float4 qa = *(const float4*)(qrow + kg * 8);
    float4 qb = *(const float4*)(qrow + kg * 8 + 4);
    float4 qc = *(const float4*)(qrow + 32 + kg * 8);
    float4 qd = *(const float4*)(qrow + 32 + kg * 8 + 4);
    uint4 af[4][2];
    #pragma unroll
    for (int mt = 0; mt < 4; ++mt)
        #pragma unroll
        for (int c = 0; c < 2; ++c)
            af[mt][c] = *(const uint4*)(ct + (mt * 16 + p16) * E_DIM + c * 32 + kg * 8);
    #pragma unroll
    for (int mt = 0; mt < 4; ++mt) {
        float4 v = *(const float4*)(bm + mt * 16 + kg * 4);
        acc[mt][0] = v.x; acc[mt][1] = v.y; acc[mt][2] = v.z; acc[mt][3] = v.w;
    }
    uint4 b0u, b1u;
    b0u.x = pk2rne(qa.x, qa.y); b0u.y = pk2rne(qa.z, qa.w);
    b0u.z = pk2rne(qb.x, qb.y); b0u.w = pk2rne(qb.z, qb.w);
    b1u.x = pk2rne(qc.x, qc.y); b1u.y = pk2rne(qc.z, qc.w);
    b1u.z = pk2rne(qd.x, qd.y); b1u.w = pk2rne(qd.z, qd.w);
    short8 b0 = as_s8(b0u), b1 = as_s8(b1u);
    #pragma unroll
    for (int mt = 0; mt < 4; ++mt)
        acc[mt] = __builtin_amdgcn_mfma_f32_16x16x32_bf16(as_s8(af[mt][0]), b0, acc[mt], 0, 0, 0);
    #pragma unroll
    for (int mt = 0; mt < 4; ++mt)
        acc[mt] = __builtin_amdgcn_mfma_f32_16x16x32_bf16(as_s8(af[mt][1]), b1, acc[mt], 0, 0, 0);
}

// Precompute Ct[m][e] bf16, bm, wbar, bbar, rm0, p0; zero wsum/emsum.
__global__ void k_pre(const float* __restrict__ q2k_w, const float* __restrict__ q2k_b,
                      const float* __restrict__ mkeys,
                      const float* __restrict__ ev_w, const float* __restrict__ ev_b,
                      const float* __restrict__ means, const float* __restrict__ logvars,
                      float* __restrict__ ws) {
    int gid = blockIdx.x * blockDim.x + threadIdx.x;
    if (gid < PRE_CT_END) {
        int e = gid >> 6, m = gid & 63;
        float s = 0.f;
        #pragma unroll
        for (int k = 0; k < KEY_DIM; ++k) s = fmaf(q2k_w[e * KEY_DIM + k], mkeys[m * KEY_DIM + k], s);
        ((unsigned short*)ws)[m * E_DIM + e] = bf16rne(s);   // transposed store
    } else if (gid < PRE_BM_END) {
        int m = gid - PRE_CT_END;
        float s = 0.f;
        #pragma unroll
        for (int k = 0; k < KEY_DIM; ++k) s = fmaf(q2k_b[k], mkeys[m * KEY_DIM + k], s);
        ws[OFF_BM + m] = s;
    } else if (gid < PRE_WBAR_END) {
        int e = gid - PRE_BM_END;
        float s = 0.f;
        for (int v = 0; v < V_DIM; ++v) s += ev_w[e * V_DIM + v];
        ws[OFF_WBAR + e] = s * (1.0f / V_DIM);
    } else if (gid == PRE_BBAR) {
        float s = 0.f;
        for (int v = 0; v < V_DIM; ++v) s += ev_b[v];
        ws[OFF_BBAR] = s * (1.0f / V_DIM);
    } else if (gid >= PRE_RM_BEG && gid < PRE_RM_END) {
        int m = gid - PRE_RM_BEG;
        const float4* mr = (const float4*)(means + (size_t)m * V_DIM);
        float s = 0.f;
        #pragma unroll
        for (int i = 0; i < V_DIM / 4; ++i) { float4 v = mr[i]; s += (v.x + v.y) + (v.z + v.w); }
        ws[OFF_RM0 + m] = s * (1.0f / V_DIM);
        ws[OFF_P0 + m]  = __expf(-logvars[(size_t)m * V_DIM]);  // row-uniform by construction
    } else if (gid >= PRE_Z_BEG && gid < PRE_Z_END) {
        ws[OFF_WSUM + (gid - PRE_Z_BEG)] = 0.f;
    }
}

// Stats-only attention, 16 pairs/wave. Grid (S, B/64), 256 threads (4 waves).
__global__ __launch_bounds__(256, 4) void k_attn(
    const float* __restrict__ qtab, const int* __restrict__ qs, const int* __restrict__ rs,
    const float* __restrict__ ws_ro,
    const float* __restrict__ qa_w, const float* __restrict__ qa_b,
    float* __restrict__ wsum, float* __restrict__ emsum,
    int B, float invNQ)
{
    __shared__ float4 lsEv[64];
    const int tid = threadIdx.x, wv = tid >> 6, lane = tid & 63;
    const int p16 = lane & 15, kg = lane >> 4;
    const int t = blockIdx.x;
    const int b = blockIdx.y * 64 + wv * 16 + p16;

    const int q = qs[(size_t)b * S_LEN + t];
    const int r = rs[(size_t)b * S_LEN + t];

    if (tid < 64) lsEv[tid] = make_float4(qa_w[tid], qa_w[E_DIM + tid], qa_b[tid],
                                          ws_ro[OFF_WBAR + tid]);
    const float bb = ws_ro[OFF_BBAR];

    f32x4 acc[4];
    mfma_logits16(qtab + (size_t)q * E_DIM, (const unsigned short*)ws_ro,
                  ws_ro + OFF_BM, kg, p16, acc);

    // softmax over 64 m of pair p16 (this lane holds 16 of them)
    float ex[16];
    float ssum = 0.f;
    #pragma unroll
    for (int mt = 0; mt < 4; ++mt)
        #pragma unroll
        for (int rg = 0; rg < 4; ++rg) {
            float e = __expf(acc[mt][rg]);
            ex[mt * 4 + rg] = e;
            ssum += e;
        }
    ssum += __shfl_xor(ssum, 16);
    ssum += __shfl_xor(ssum, 32);
    const float inv = __fdividef(1.0f, ssum);

    // fold normalized attn over the 16 pairs; lane ends with index jj=lane&15
    float av[16];
    #pragma unroll
    for (int j = 0; j < 16; ++j) av[j] = ex[j] * inv;
    #pragma unroll
    for (int step = 0; step < 4; ++step) {
        const int sh = 1 << step;
        #pragma unroll
        for (int j = 0; j < (16 >> step) / 2; ++j) {
            float p0 = av[2 * j]     + __shfl_xor(av[2 * j], sh);
            float p1 = av[2 * j + 1] + __shfl_xor(av[2 * j + 1], sh);
            av[j] = (lane & sh) ? p1 : p0;
        }
    }
    {
        const int jj = lane & 15;
        const int m = (jj >> 2) * 16 + kg * 4 + (jj & 3);
        atomicAdd(&wsum[t * M_SLOTS + m], av[0]);
    }

    __syncthreads();   // lsEv ready

    // evidence scalar: kg covers e = kg*16..+15; combine 4 kg slices, fold 16 pairs
    float qn = (float)q * invNQ;
    float rn = (float)r * (1.0f / (K_CAT - 1));
    float evm = 0.f;
    #pragma unroll
    for (int i = 0; i < 16; ++i) {
        float4 pv = lsEv[kg * 16 + i];
        float qa = fmaf(qn, pv.x, fmaf(rn, pv.y, pv.z));
        float ez = __expf(2.0f * qa);
        evm = fmaf(__fdividef(ez - 1.0f, ez + 1.0f), pv.w, evm);
    }
    evm += __shfl_xor(evm, 16);
    evm += __shfl_xor(evm, 32);
    evm += bb;
    #pragma unroll
    for (int o = 8; o; o >>= 1) evm += __shfl_xor(evm, o);  // sum 16 pairs
    if (!lane) atomicAdd(&emsum[t], evm);
}

// Output: 4-wave-parallel associative prefix for rm_t (natural m order now),
// then MFMA recompute, softmax, theta dot, GPCM. Grid (S, B/64), 256 threads.
__global__ __launch_bounds__(256, 4) void k_out(
    const float* __restrict__ qtab, const int* __restrict__ qs,
    const float* __restrict__ ws_ro,
    const float* __restrict__ alpha_mean, const float* __restrict__ beta_base,
    const float* __restrict__ beta_gaps, float* __restrict__ out, int B, float invB)
{
    __shared__ float lsW[4][M_SLOTS], lsN[4][M_SLOTS];
    __shared__ float lsRm[M_SLOTS];
    const int tid = threadIdx.x, wv = tid >> 6, lane = tid & 63;
    const int p16 = lane & 15, kg = lane >> 4;
    const int t = blockIdx.x;
    const int b = blockIdx.y * 64 + wv * 16 + p16;

    const int q = qs[(size_t)b * S_LEN + t];

    // prefix partials: wave wv sums segment [s0,s1) over m=lane (associative)
    {
        const float* wsum  = ws_ro + OFF_WSUM;
        const float* emsum = ws_ro + OFF_EMSUM;
        const int seg = (t + 3) >> 2;
        const int s0 = wv * seg, s1 = min(s0 + seg, t);
        float pw = 0.f, pn = 0.f;
        for (int s = s0; s < s1; ++s) {
            float w = wsum[s * M_SLOTS + lane];
            pw += w;
            pn = fmaf(emsum[s], w, pn);
        }
        lsW[wv][lane] = pw; lsN[wv][lane] = pn;
    }
    __syncthreads();
    if (tid < 64) {
        const int m = tid;
        float sw = lsW[0][m] + lsW[1][m] + lsW[2][m] + lsW[3][m];
        float sn = lsN[0][m] + lsN[1][m] + lsN[2][m] + lsN[3][m];
        float den = ws_ro[OFF_P0 + m] + sw * invB;
        float num = ws_ro[OFF_P0 + m] * ws_ro[OFF_RM0 + m] + sn * (invB * invB);
        lsRm[m] = num / den;   // state BEFORE update at t; natural order
    }
    __syncthreads();

    f32x4 acc[4];
    mfma_logits16(qtab + (size_t)q * E_DIM, (const unsigned short*)ws_ro,
                  ws_ro + OFF_BM, kg, p16, acc);

    float ssum = 0.f, th = 0.f;
    #pragma unroll
    for (int mt = 0; mt < 4; ++mt)
        #pragma unroll
        for (int rg = 0; rg < 4; ++rg) {
            float e = __expf(acc[mt][rg]);
            ssum += e;
            th = fmaf(e, lsRm[mt * 16 + kg * 4 + rg], th);
        }
    ssum += __shfl_xor(ssum, 16);
    ssum += __shfl_xor(ssum, 32);
    th   += __shfl_xor(th, 16);
    th   += __shfl_xor(th, 32);
    th = __fdividef(th, ssum);

    if (kg == 0) gpcm_store(th, q, alpha_mean, beta_base, beta_gaps, out, (size_t)b * S_LEN + t);
}

extern "C" void kernel_launch(void* const* d_in, const int* in_sizes, int n_in,
                              void* d_out, int out_size, void* d_ws, size_t ws_size,
                              hipStream_t stream) {
    const float* qtab       = (const float*)d_in[0];
    const float* alpha_mean = (const float*)d_in[1];
    const float* beta_base  = (const float*)d_in[2];
    const float* beta_gaps  = (const float*)d_in[3];
    const float* ab_means   = (const float*)d_in[4];
    const float* ab_logvars = (const float*)d_in[5];
    const float* mkeys      = (const float*)d_in[6];
    const float* q2k_w      = (const float*)d_in[7];
    const float* q2k_b      = (const float*)d_in[8];
    const float* qa_w       = (const float*)d_in[9];
    const float* qa_b       = (const float*)d_in[10];
    const float* ev_w       = (const float*)d_in[11];
    const float* ev_b       = (const float*)d_in[12];
    const int*   qs         = (const int*)d_in[13];
    const int*   rs         = (const int*)d_in[14];
    float* out = (float*)d_out;
    float* ws  = (float*)d_ws;

    const int NQ = in_sizes[1];
    const int S  = S_LEN;
    const int B  = in_sizes[13] / S;   // 512

    float* wsum  = ws + OFF_WSUM;
    float* emsum = ws + OFF_EMSUM;

    k_pre<<<(PRE_Z_END + 255) / 256, 256, 0, stream>>>(
        q2k_w, q2k_b, mkeys, ev_w, ev_b, ab_means, ab_logvars, ws);

    dim3 g(S, B / 64);
    k_attn<<<g, 256, 0, stream>>>(qtab, qs, rs, ws, qa_w, qa_b,
                                  wsum, emsum, B, 1.0f / (float)NQ);

    k_out<<<g, 256, 0, stream>>>(qtab, qs, ws, alpha_mean, beta_base,
                                 beta_gaps, out, B, 1.0f / (float)B);
}